// Round 4
// baseline (168.825 us; speedup 1.0000x reference)
//
#include <hip/hip_runtime.h>

// LengthRegulator: B=32, T=512, D=512, max_len=2048 (fixed by the problem).
// out[b, t, :] = x[b, searchsorted_right(cumsum(duration[b]), t), :] for
// t < sum(duration[b]), else zeros. mel_lengths[b] = max(sum, 1), stored as
// float at the tail of d_out (harness reads whole buffer as float32).
//
// Evidence from rounds 0-2: three different block-owned-region copies all ran
// at ~2 TB/s, while the harness's own 512 MiB poison fill runs at 6.4 TB/s at
// 9% occupancy. Difference is the instantaneous address front: fill is a
// grid-stride SWEEP (whole grid writes one contiguous slab, advancing), ours
// were ~10k scattered per-wave streams (DRAM row thrash). This version copies
// the fill's shape exactly:
//
//   A) lr_scan_kernel (32 blocks): wave-shfl cumsum of duration, scatter
//      frame->phoneme table idxt[b][t] into d_ws (-1 = padding), mel tail.
//   B) lr_sweep_kernel (2048 x 256 = 2^19 threads): grid-stride over the flat
//      f4 output space, stride 2^19. Thread g, step k handles flat element
//      e = g + k*2^19: d4 = g&127, t = (g>>7)&2047 (fixed per thread),
//      b = 2k + (g>>18). Grid writes one contiguous 8 MiB (2-batch) slab per
//      step, 16 steps -- identical front to the fill. x reads sweep forward
//      too (idx monotone in t); idxt loads wave-uniform, prefetched 8-ahead.
//      Plain stores (the fill's proven 6.4 TB/s mode).
//
// (Round 3 submission failed with a container-acquisition infra error, not a
// kernel error; this is an unchanged resubmission to obtain the measurement.)

#define BB      32
#define TT      512
#define DD      512
#define MAXLEN  2048
#define RPF     (DD / 4)            // 128 f4 per frame row
#define GTH     (1 << 19)           // sweep threads = 524288
#define NSWEEP  16                  // (BB*MAXLEN*RPF) / GTH

typedef float f4 __attribute__((ext_vector_type(4)));

__global__ __launch_bounds__(512) void lr_scan_kernel(
    const int* __restrict__ dur, int* __restrict__ idxt,
    float* __restrict__ mel_out) {
  __shared__ int wsum[8];
  const int b    = blockIdx.x;
  const int tid  = threadIdx.x;
  const int lane = tid & 63;
  const int wid  = tid >> 6;

  const int d = dur[b * TT + tid];
  int v = d;
  // Inclusive scan within the 64-lane wave (6 shfl steps, no barriers).
#pragma unroll
  for (int off = 1; off < 64; off <<= 1) {
    int n = __shfl_up(v, off, 64);
    if (lane >= off) v += n;
  }
  if (lane == 63) wsum[wid] = v;
  __syncthreads();

  int woff = 0, dsum = 0;
#pragma unroll
  for (int i = 0; i < 8; ++i) {
    int w = wsum[i];
    dsum += w;
    if (i < wid) woff += w;
  }
  v += woff;  // inclusive cumsum at phoneme tid

  if (tid == 0) mel_out[b] = (float)(dsum > 1 ? dsum : 1);

  // Scatter: phoneme tid owns output frames [v - d, v), truncated at MAXLEN.
  int start = v - d;
  int end   = v;
  if (start > MAXLEN) start = MAXLEN;
  if (end   > MAXLEN) end   = MAXLEN;
  int* row = idxt + b * MAXLEN;
  for (int t = start; t < end; ++t) row[t] = tid;
  // Padding tail [dsum, MAXLEN): coalesced -1 fill.
  for (int t = dsum + tid; t < MAXLEN; t += TT) row[t] = -1;
}

__global__ __launch_bounds__(256) void lr_sweep_kernel(
    const int* __restrict__ idxt, const f4* __restrict__ x,
    f4* __restrict__ out) {
  const int g  = blockIdx.x * 256 + threadIdx.x;
  const int d4 = g & (RPF - 1);            // f4 lane within row, wave-coalesced
  const int t  = (g >> 7) & (MAXLEN - 1);  // frame index, fixed across sweeps
  const int hi = g >> 18;                  // 0/1: which batch of the slab pair
  const f4 zero = {0.f, 0.f, 0.f, 0.f};

#pragma unroll
  for (int h = 0; h < 2; ++h) {
    int idxv[8];
#pragma unroll
    for (int k = 0; k < 8; ++k) {
      const int b = 2 * (h * 8 + k) + hi;
      idxv[k] = idxt[b * MAXLEN + t];      // wave-uniform, L2-hot
    }
#pragma unroll
    for (int k = 0; k < 8; ++k) {
      const int kk = h * 8 + k;
      const int b  = 2 * kk + hi;
      const int idx = idxv[k];             // wave-uniform -> no divergence
      f4 v = zero;
      if (idx >= 0) {
        v = x[((size_t)b * TT + idx) * RPF + d4];
      }
      out[(size_t)g + (size_t)kk * GTH] = v;  // grid-wide contiguous front
    }
  }
}

extern "C" void kernel_launch(void* const* d_in, const int* in_sizes, int n_in,
                              void* d_out, int out_size, void* d_ws, size_t ws_size,
                              hipStream_t stream) {
  const float* x   = (const float*)d_in[0];
  const int*   dur = (const int*)d_in[1];
  // d_in[2] is max_len (=2048), static; hard-coded.
  float* out = (float*)d_out;
  float* mel_out = out + (size_t)BB * MAXLEN * DD;  // tail: 32 floats
  int* idxt = (int*)d_ws;                           // 32*2048*4 = 256 KiB

  lr_scan_kernel<<<BB, 512, 0, stream>>>(dur, idxt, mel_out);
  lr_sweep_kernel<<<GTH / 256, 256, 0, stream>>>(idxt, (const f4*)x, (f4*)out);
}